// Round 4
// baseline (297.694 us; speedup 1.0000x reference)
//
#include <hip/hip_runtime.h>

#define NPTS  4096
#define MQ    1024
#define BATCH 16
#define KNN   32
#define CIN   64
#define H1D   64
#define H2D   128

typedef _Float16 half8 __attribute__((ext_vector_type(8)));
typedef float    floatx4 __attribute__((ext_vector_type(4)));

// ws layout: nn [2 MB] | W1f+W2f fragments [28 KB] | pos4 [1 MB]
#define WS_NN_BYTES ((size_t)BATCH * MQ * KNN * 4)
#define W1F_HALVES  (3 * 4 * 64 * 8)
#define W2F_HALVES  (2 * 8 * 64 * 8)
#define WS_P4_OFF   (WS_NN_BYTES + (W1F_HALVES + W2F_HALVES) * 2)

// ---------------------------------------------------------------------------
// Kernel 0: pack W1/W2 into f16 MFMA B-fragment layout + pack pos into
// float4 {x,y,z,|p|^2}  (|p|^2 with the exact reference association).
// ---------------------------------------------------------------------------
__global__ __launch_bounds__(256) void wprep_kernel(
    const float* __restrict__ W1, const float* __restrict__ W2,
    const float* __restrict__ pos,
    _Float16* __restrict__ wout, float4* __restrict__ pos4)
{
    const int gid = blockIdx.x * 256 + threadIdx.x;
    if (gid < 768) {                                 // W1 fragments
        const int s = gid;
        const int kc = s >> 8, nt = (s >> 6) & 3, lane = s & 63;
        const int col = lane & 15, quad = lane >> 4;
        half8 ph;
#pragma unroll
        for (int j = 0; j < 8; ++j) {
            const int k = kc * 32 + quad * 8 + j;
            ph[j] = (k < 67) ? (_Float16)W1[k * H1D + nt * 16 + col] : (_Float16)0.0f;
        }
        *(half8*)(wout + (size_t)s * 8) = ph;
    } else if (gid < 1792) {                         // W2 fragments
        const int s2 = gid - 768;
        const int kc2 = s2 >> 9, nt2 = (s2 >> 6) & 7, lane = s2 & 63;
        const int col = lane & 15, quad = lane >> 4;
        half8 ph;
#pragma unroll
        for (int j = 0; j < 8; ++j) {
            const int k = kc2 * 32 + quad * 8 + j;
            ph[j] = (_Float16)W2[k * H2D + nt2 * 16 + col];
        }
        *(half8*)(wout + (size_t)W1F_HALVES + (size_t)s2 * 8) = ph;
    } else {                                         // pos4 for all B*N points
        const int p = gid - 1792;
        if (p < BATCH * NPTS) {
            const float px = pos[p * 3 + 0], py = pos[p * 3 + 1], pz = pos[p * 3 + 2];
            float4 v;
            v.x = px; v.y = py; v.z = pz;
            v.w = __fadd_rn(__fadd_rn(__fmul_rn(px, px), __fmul_rn(py, py)),
                            __fmul_rn(pz, pz));
            pos4[p] = v;
        }
    }
}

// ---------------------------------------------------------------------------
// Kernel 1: exact KNN, quad-threshold select, 4 queries per block.
// r10: r9's slab design collapsed parallelism (512 blocks, VGPR 172, occ 11%,
// latency-bound at 148 us). Revert to the high-parallelism r6 shape (points
// in registers, 16/thread) but with the cheap threshold select instead of
// histograms: quad-group minima (2 shfl_xor), T = 32nd-smallest of the 64
// quad minima via the r9-VERIFIED 21-step bitonic on wave 0 (>=32 disjoint
// 64-pt groups have min <= T  =>  >=32 keys <= T, guaranteed; ~44 candidates
// expected), compact via LDS atomics, exact lex (key,idx) rank. 4 queries
// amortize one p[16] register load -> L2 slab traffic 1 GB -> 256 MB.
// VGPR ~110, LDS ~1.3 KB -> ~3 blocks/CU resident, 16 queued. Same bit-keys
// + tie-break as the verified r2 kernel; 32-pass extraction fallback keeps
// exactness unconditional.
// ---------------------------------------------------------------------------
#define QPB  4
#define CCAP 128
__global__ __launch_bounds__(256, 3) void knn_kernel(
    const float4* __restrict__ pos4, const int* __restrict__ idx,
    float* __restrict__ pos_q, int* __restrict__ nn)
{
    const int bid = blockIdx.x;          // 4096 blocks: 256 per batch
    const int b   = bid >> 8;
    const int mb  = (bid & 255) * QPB;
    const int t   = threadIdx.x;
    const int wv  = t >> 6, lane = t & 63;

    __shared__ unsigned int gmin[64];
    __shared__ uint2 cand[CCAP];         // 1 KB
    __shared__ unsigned int sc[2];       // [0]=T, [1]=candidate count
    __shared__ unsigned long long w64[4];

    const float4* pb4 = pos4 + (size_t)b * NPTS;

    // preload this thread's 16 points once; reused by all 4 queries
    float4 p[16];
#pragma unroll
    for (int i = 0; i < 16; ++i) p[i] = pb4[i * 256 + t];

    for (int qi = 0; qi < QPB; ++qi) {
        const int q  = b * MQ + mb + qi;
        const int qn = idx[q];
        const float4 qv = pb4[qn];       // same addr all lanes -> broadcast
        const float qq = qv.w;

        // keys: monotone-mapped fp32 d2, bitwise identical association:
        // d2 = (qq + |p|^2) - 2*dot(q,p)
        unsigned int k[16];
        unsigned int lmin = 0xFFFFFFFFu;
#pragma unroll
        for (int i = 0; i < 16; ++i) {
            const float qp = __fadd_rn(__fadd_rn(__fmul_rn(qv.x, p[i].x), __fmul_rn(qv.y, p[i].y)),
                                       __fmul_rn(qv.z, p[i].z));
            const float d2 = __fsub_rn(__fadd_rn(qq, p[i].w), __fmul_rn(2.0f, qp));
            unsigned int u = __float_as_uint(d2);
            u = (u & 0x80000000u) ? ~u : (u | 0x80000000u);
            k[i] = u;
            lmin = min(lmin, u);
        }

        // quad minima: threads {t&~3 .. t&~3|3} cover 64 disjoint points
        lmin = min(lmin, (unsigned int)__shfl_xor((int)lmin, 1));
        lmin = min(lmin, (unsigned int)__shfl_xor((int)lmin, 2));
        if ((t & 3) == 0) gmin[t >> 2] = lmin;
        if (t == 0) sc[1] = 0u;
        __syncthreads();                 // A: gmin + counter reset visible

        // wave 0: bitonic sort the 64 quad minima; T = value at rank 31
        if (wv == 0) {
            unsigned int v = gmin[lane];
#pragma unroll
            for (int kk = 2; kk <= 64; kk <<= 1) {
#pragma unroll
                for (int j = kk >> 1; j > 0; j >>= 1) {
                    const unsigned int o = (unsigned int)__shfl_xor((int)v, j);
                    const bool keepSmall = (((lane & kk) == 0) == ((lane & j) == 0));
                    v = keepSmall ? min(v, o) : max(v, o);
                }
            }
            if (lane == 31) sc[0] = v;
        }
        __syncthreads();                 // B: T visible
        const unsigned int T = sc[0];

        // scatter candidates: every key <= T (guaranteed >= 32 of them)
#pragma unroll
        for (int i = 0; i < 16; ++i) {
            if (k[i] <= T) {
                const unsigned int slot = atomicAdd(&sc[1], 1u);
                if (slot < (unsigned)CCAP)
                    cand[slot] = make_uint2(k[i], (unsigned int)(i * 256 + t));
            }
        }
        __syncthreads();                 // C: candidates visible
        const int C = (int)sc[1];

        if (C <= CCAP) {
            // exact lex rank among candidates; global top-32 all have key <= T
            if (t < C) {
                const uint2 my = cand[t];
                int rk = 0;
                for (int j = 0; j < C; ++j) {
                    const uint2 cj = cand[j];    // broadcast read
                    rk += (cj.x < my.x || (cj.x == my.x && cj.y < my.y)) ? 1 : 0;
                }
                if (rk < KNN) nn[(size_t)q * KNN + rk] = (int)my.y;
            }
        } else {
            // fallback (never expected): exact 32-pass lex min-extraction
            unsigned long long last = 0ull;
            for (int r = 0; r < KNN; ++r) {
                __syncthreads();
                unsigned long long best = ~0ull;
#pragma unroll
                for (int i = 0; i < 16; ++i) {
                    const unsigned long long pk =
                        ((unsigned long long)k[i] << 32) | (unsigned int)(i * 256 + t);
                    if ((r == 0 || pk > last) && pk < best) best = pk;
                }
#pragma unroll
                for (int off = 1; off < 64; off <<= 1) {
                    const unsigned long long ob = __shfl_xor(best, off);
                    if (ob < best) best = ob;
                }
                if (lane == 0) w64[wv] = best;
                __syncthreads();
                if (t == 0) {
                    unsigned long long bb = w64[0];
                    for (int wi = 1; wi < 4; ++wi) if (w64[wi] < bb) bb = w64[wi];
                    w64[0] = bb;
                    nn[(size_t)q * KNN + r] = (int)(bb & 0xFFFFFFFFu);
                }
                __syncthreads();
                last = w64[0];
            }
        }

        if (t == 0) {
            pos_q[(size_t)q * 3 + 0] = qv.x;
            pos_q[(size_t)q * 3 + 1] = qv.y;
            pos_q[(size_t)q * 3 + 2] = qv.z;
        }
        __syncthreads();                 // D: protect gmin/cand/sc reuse
    }
}

// ---------------------------------------------------------------------------
// Kernel 2: fused gather + MLP via f16 MFMA 16x16x32 + max over K.
// r6 restructure: weights live in per-wave VGPRs (not LDS) -> zero barriers,
// LDS 24 KB (wave-private X/H1 fragment region only). Fragment math identical
// to the r3-verified kernel (absmax 0.031).
// r10: launch_bounds (256,4)->(256,3). The fragment working set (w1f 48 +
// w2f 64 + af 24 + a2 16 + ff 48 VGPRs, partially overlapping live ranges)
// cannot fit the (256,4) 128-VGPR cap -> suspected scratch spills / strangled
// load scheduling. Cap 170 VGPRs, ~12 waves/CU.
// ---------------------------------------------------------------------------
__global__ __launch_bounds__(256, 3) void mlp_kernel(
    const float4* __restrict__ pos4, const float* __restrict__ feat,
    const float* __restrict__ b1, const float* __restrict__ b2,
    const float* __restrict__ pos_q, const int* __restrict__ nn,
    const _Float16* __restrict__ wf, float* __restrict__ out)
{
    __shared__ _Float16 sh[4 * 3072];       // 24 KB, wave-private 6 KB regions
    const int t = threadIdx.x;
    const int w = t >> 6, lane = t & 63;
    const int col = lane & 15, quad = lane >> 4;
    const int q = blockIdx.x * 4 + w;       // wave-uniform query id
    const int b = q >> 10;
    const int wbase = w * 3072;

    // gather + pack X A-frags (2 threads per neighbor row; rows of query w
    // are handled entirely by wave w -> wave-private, no barrier needed)
    {
        const int r = t >> 1, h = t & 1;
        const int kk = r & 31;
        const int n = nn[(size_t)q * KNN + kk];
        const float4 pv = pos4[(size_t)b * NPTS + n];
        const float4* f4 = (const float4*)(feat + ((size_t)b * NPTS + n) * CIN);
        const int mt = kk >> 4, lrow = kk & 15;
        if (h == 0) {                        // cols 0..47: rel(3) + feat[0..44]
            float4 ff[12];
#pragma unroll
            for (int ii = 0; ii < 12; ++ii) ff[ii] = f4[ii];
            float rel[3];
            rel[0] = pv.x - pos_q[(size_t)q * 3 + 0];
            rel[1] = pv.y - pos_q[(size_t)q * 3 + 1];
            rel[2] = pv.z - pos_q[(size_t)q * 3 + 2];
#pragma unroll
            for (int ci = 0; ci < 6; ++ci) {
                half8 ph;
#pragma unroll
                for (int jj = 0; jj < 8; ++jj) {
                    const int c = ci * 8 + jj;
                    float v;
                    if (c < 3) v = rel[c];
                    else {
                        const int fc = c - 3;
                        const float4 vv = ff[fc >> 2];
                        v = ((fc & 3) == 0) ? vv.x : ((fc & 3) == 1) ? vv.y
                          : ((fc & 3) == 2) ? vv.z : vv.w;
                    }
                    ph[jj] = (_Float16)v;
                }
                const int kc = ci >> 2, qd = ci & 3;
                *(half8*)&sh[wbase + ((kc * 2 + mt) * 64 + qd * 16 + lrow) * 8] = ph;
            }
        } else {                             // cols 48..95: feat[45..63] + pad
            float4 ff[5];
#pragma unroll
            for (int ii = 0; ii < 5; ++ii) ff[ii] = f4[11 + ii];
#pragma unroll
            for (int ci = 6; ci < 12; ++ci) {
                half8 ph;
#pragma unroll
                for (int jj = 0; jj < 8; ++jj) {
                    const int c = ci * 8 + jj;
                    float v = 0.0f;
                    if (c < 67) {
                        const int fc = c - 3;            // 45..63
                        const float4 vv = ff[(fc >> 2) - 11];
                        v = ((fc & 3) == 0) ? vv.x : ((fc & 3) == 1) ? vv.y
                          : ((fc & 3) == 2) ? vv.z : vv.w;
                    }
                    ph[jj] = (_Float16)v;
                }
                const int kc = ci >> 2, qd = ci & 3;
                *(half8*)&sh[wbase + ((kc * 2 + mt) * 64 + qd * 16 + lrow) * 8] = ph;
            }
        }
    }
    // no __syncthreads(): all LDS traffic below is same-wave, DS pipe in-order

    // layer 1: A-frags from LDS, W1 B-frags from global into VGPRs
    half8 af[3][2];
#pragma unroll
    for (int kc = 0; kc < 3; ++kc)
#pragma unroll
        for (int mt = 0; mt < 2; ++mt)
            af[kc][mt] = *(const half8*)&sh[wbase + ((kc * 2 + mt) * 64 + lane) * 8];

    half8 w1f[3][4];
#pragma unroll
    for (int kc = 0; kc < 3; ++kc)
#pragma unroll
        for (int nt = 0; nt < 4; ++nt)
            w1f[kc][nt] = *(const half8*)(wf + (size_t)((kc * 4 + nt) * 64 + lane) * 8);

#pragma unroll
    for (int nt = 0; nt < 4; ++nt) {
        const float bv = b1[nt * 16 + col];
        floatx4 acc0 = {bv, bv, bv, bv}, acc1 = acc0;
#pragma unroll
        for (int kc = 0; kc < 3; ++kc) {
            acc0 = __builtin_amdgcn_mfma_f32_16x16x32_f16(af[kc][0], w1f[kc][nt], acc0, 0, 0, 0);
            acc1 = __builtin_amdgcn_mfma_f32_16x16x32_f16(af[kc][1], w1f[kc][nt], acc1, 0, 0, 0);
        }
        const int kc2 = nt >> 1;
        const int quad2 = (((nt & 1) * 16) + col) >> 3;
        const int j2 = col & 7;
#pragma unroll
        for (int mt = 0; mt < 2; ++mt) {
            const floatx4 a = mt ? acc1 : acc0;
#pragma unroll
            for (int reg = 0; reg < 4; ++reg) {
                const int row = quad * 4 + reg;
                sh[wbase + ((kc2 * 2 + mt) * 64 + quad2 * 16 + row) * 8 + j2] =
                    (_Float16)fmaxf(a[reg], 0.0f);
            }
        }
    }

    // layer 2 + max over K
    half8 a2[2][2];
#pragma unroll
    for (int kc2 = 0; kc2 < 2; ++kc2)
#pragma unroll
        for (int mt = 0; mt < 2; ++mt)
            a2[kc2][mt] = *(const half8*)&sh[wbase + ((kc2 * 2 + mt) * 64 + lane) * 8];

    half8 w2f[2][8];
#pragma unroll
    for (int kc2 = 0; kc2 < 2; ++kc2)
#pragma unroll
        for (int nt2 = 0; nt2 < 8; ++nt2)
            w2f[kc2][nt2] = *(const half8*)(wf + (size_t)W1F_HALVES
                                            + (size_t)((kc2 * 8 + nt2) * 64 + lane) * 8);

    float* oq = out + (size_t)q * H2D;
#pragma unroll
    for (int nt2 = 0; nt2 < 8; ++nt2) {
        const float bv = b2[nt2 * 16 + col];
        floatx4 acc0 = {bv, bv, bv, bv}, acc1 = acc0;
#pragma unroll
        for (int kc2 = 0; kc2 < 2; ++kc2) {
            acc0 = __builtin_amdgcn_mfma_f32_16x16x32_f16(a2[kc2][0], w2f[kc2][nt2], acc0, 0, 0, 0);
            acc1 = __builtin_amdgcn_mfma_f32_16x16x32_f16(a2[kc2][1], w2f[kc2][nt2], acc1, 0, 0, 0);
        }
        float mm = fmaxf(fmaxf(fmaxf(acc0[0], acc0[1]), fmaxf(acc0[2], acc0[3])),
                         fmaxf(fmaxf(acc1[0], acc1[1]), fmaxf(acc1[2], acc1[3])));
        mm = fmaxf(mm, 0.0f);
        mm = fmaxf(mm, __shfl_xor(mm, 16));
        mm = fmaxf(mm, __shfl_xor(mm, 32));
        if (lane < 16) oq[nt2 * 16 + lane] = mm;
    }
}

extern "C" void kernel_launch(void* const* d_in, const int* in_sizes, int n_in,
                              void* d_out, int out_size, void* d_ws, size_t ws_size,
                              hipStream_t stream)
{
    const float* pos  = (const float*)d_in[0];
    const float* feat = (const float*)d_in[1];
    const float* W1   = (const float*)d_in[2];
    const float* b1   = (const float*)d_in[3];
    const float* W2   = (const float*)d_in[4];
    const float* b2   = (const float*)d_in[5];
    const int*   idx  = (const int*)d_in[6];   // int64 delivered as int32

    float* pos_q = (float*)d_out;
    float* out   = (float*)d_out + (size_t)BATCH * MQ * 3;
    int*      nn = (int*)d_ws;
    _Float16* wf = (_Float16*)((char*)d_ws + WS_NN_BYTES);
    float4*   p4 = (float4*)((char*)d_ws + WS_P4_OFF);

    const int prep_threads = 1792 + BATCH * NPTS;
    wprep_kernel<<<(prep_threads + 255) / 256, 256, 0, stream>>>(W1, W2, pos, wf, p4);
    knn_kernel<<<BATCH * MQ / QPB, 256, 0, stream>>>(p4, idx, pos_q, nn);
    mlp_kernel<<<BATCH * MQ / 4, 256, 0, stream>>>(p4, feat, b1, b2,
                                                   pos_q, nn, wf, out);
}

// Round 5
// 188.303 us; speedup vs baseline: 1.5809x; 1.5809x over previous
//
#include <hip/hip_runtime.h>

#define NPTS  4096
#define MQ    1024
#define BATCH 16
#define KNN   32
#define CIN   64
#define H1D   64
#define H2D   128

typedef _Float16 half8 __attribute__((ext_vector_type(8)));
typedef float    floatx4 __attribute__((ext_vector_type(4)));

// ws layout: nn [2 MB] | W1f+W2f fragments [28 KB] | pos4 [1 MB] | x16 [12.6 MB]
#define WS_NN_BYTES ((size_t)BATCH * MQ * KNN * 4)
#define W1F_HALVES  (3 * 4 * 64 * 8)
#define W2F_HALVES  (2 * 8 * 64 * 8)
#define WS_P4_OFF   (WS_NN_BYTES + (W1F_HALVES + W2F_HALVES) * 2)
#define WS_X16_OFF  (WS_P4_OFF + (size_t)BATCH * NPTS * 16)
#define XROW        96    // halves per padded point row: [0,0,0, feat64, 0 x29]

// ---------------------------------------------------------------------------
// Kernel 0: pack W1/W2 into f16 MFMA B-fragment layout, pack pos into
// float4 {x,y,z,|p|^2} (exact reference association), and NEW in r11:
// pre-convert features into padded f16 rows x16[n][96] = {0,0,0, feat, 0...}
// with the SAME channel placement the mlp pack used (rel at k=0..2, feat at
// 3..66) -> MFMA inputs stay bitwise identical, mlp's 300-op/row pack chain
// (524K rows) is replaced by a once-per-point conversion here (65K rows).
// ---------------------------------------------------------------------------
__global__ __launch_bounds__(256) void wprep_kernel(
    const float* __restrict__ W1, const float* __restrict__ W2,
    const float* __restrict__ pos, const float* __restrict__ feat,
    _Float16* __restrict__ wout, float4* __restrict__ pos4,
    _Float16* __restrict__ x16)
{
    const int gid = blockIdx.x * 256 + threadIdx.x;
    if (gid < 768) {                                 // W1 fragments
        const int s = gid;
        const int kc = s >> 8, nt = (s >> 6) & 3, lane = s & 63;
        const int col = lane & 15, quad = lane >> 4;
        half8 ph;
#pragma unroll
        for (int j = 0; j < 8; ++j) {
            const int k = kc * 32 + quad * 8 + j;
            ph[j] = (k < 67) ? (_Float16)W1[k * H1D + nt * 16 + col] : (_Float16)0.0f;
        }
        *(half8*)(wout + (size_t)s * 8) = ph;
    } else if (gid < 1792) {                         // W2 fragments
        const int s2 = gid - 768;
        const int kc2 = s2 >> 9, nt2 = (s2 >> 6) & 7, lane = s2 & 63;
        const int col = lane & 15, quad = lane >> 4;
        half8 ph;
#pragma unroll
        for (int j = 0; j < 8; ++j) {
            const int k = kc2 * 32 + quad * 8 + j;
            ph[j] = (_Float16)W2[k * H2D + nt2 * 16 + col];
        }
        *(half8*)(wout + (size_t)W1F_HALVES + (size_t)s2 * 8) = ph;
    } else {                                         // per-point: pos4 + x16 row
        const int p = gid - 1792;
        if (p < BATCH * NPTS) {
            const float px = pos[p * 3 + 0], py = pos[p * 3 + 1], pz = pos[p * 3 + 2];
            float4 v;
            v.x = px; v.y = py; v.z = pz;
            v.w = __fadd_rn(__fadd_rn(__fmul_rn(px, px), __fmul_rn(py, py)),
                            __fmul_rn(pz, pz));
            pos4[p] = v;

            const float4* f4 = (const float4*)(feat + (size_t)p * CIN);
            float4 ff[16];
#pragma unroll
            for (int ii = 0; ii < 16; ++ii) ff[ii] = f4[ii];
            _Float16* xr = x16 + (size_t)p * XROW;
#pragma unroll
            for (int ci = 0; ci < 12; ++ci) {
                half8 ph;
#pragma unroll
                for (int jj = 0; jj < 8; ++jj) {
                    const int c = ci * 8 + jj;
                    float v2 = 0.0f;
                    if (c >= 3 && c < 67) {
                        const int fc = c - 3;
                        const float4 vv = ff[fc >> 2];
                        v2 = ((fc & 3) == 0) ? vv.x : ((fc & 3) == 1) ? vv.y
                           : ((fc & 3) == 2) ? vv.z : vv.w;
                    }
                    ph[jj] = (_Float16)v2;
                }
                *(half8*)(xr + ci * 8) = ph;
            }
        }
    }
}

// ---------------------------------------------------------------------------
// Kernel 1: exact KNN — r7 version restored VERBATIM (measured 83 us,
// VALUBusy ~67%, the best of r6-r10; r8-r10's threshold/slab experiments all
// regressed: serial phases + idle lanes (r8: 98 us), occupancy collapse
// (r9: 148 us), serial multi-query + barriers (r10: 192 us)). knn is
// on-chip/VALU-bound at high parallelism; keep 1 block/query, 16384 blocks.
// ---------------------------------------------------------------------------
__global__ __launch_bounds__(256, 4) void knn_kernel(
    const float4* __restrict__ pos4, const int* __restrict__ idx,
    float* __restrict__ pos_q, int* __restrict__ nn)
{
    const int bid = blockIdx.x;
    const int b   = bid >> 10;
    const int m   = bid & (MQ - 1);
    const int t   = threadIdx.x;
    const int wv  = t >> 6, lane = t & 63;

    __shared__ __align__(16) unsigned int hist[1024];   // 4 KB
    __shared__ unsigned int wred[8];                    // per-wave min/max
    __shared__ unsigned int wsum[4];
    __shared__ unsigned int sc[8];
    __shared__ unsigned int ckey[64];
    __shared__ int          cidx[64];
    __shared__ int          outidx[KNN];

    const float4* pb4 = pos4 + (size_t)b * NPTS;
    const int qn = idx[(size_t)b * MQ + m];
    const float4 qv = pb4[qn];
    const float qq = qv.w;

    // zero hist (uint4 store: 16B/lane, conflict-free)
    *(uint4*)&hist[t * 4] = make_uint4(0u, 0u, 0u, 0u);

    // preload all 16 points -> 16 loads in flight, one wait
    float4 p[16];
#pragma unroll
    for (int i = 0; i < 16; ++i) p[i] = pb4[i * 256 + t];

    unsigned int k[16];
    unsigned int lmin = 0xFFFFFFFFu, lmax = 0u;
#pragma unroll
    for (int i = 0; i < 16; ++i) {
        const float qp = __fadd_rn(__fadd_rn(__fmul_rn(qv.x, p[i].x), __fmul_rn(qv.y, p[i].y)),
                                   __fmul_rn(qv.z, p[i].z));
        const float d2 = __fsub_rn(__fadd_rn(qq, p[i].w), __fmul_rn(2.0f, qp));
        unsigned int u = __float_as_uint(d2);
        u = (u & 0x80000000u) ? ~u : (u | 0x80000000u);
        k[i] = u;
        lmin = min(lmin, u);
        lmax = max(lmax, u);
    }
    // wave reduce min/max
#pragma unroll
    for (int off = 32; off; off >>= 1) {
        lmin = min(lmin, (unsigned int)__shfl_xor(lmin, off));
        lmax = max(lmax, (unsigned int)__shfl_xor(lmax, off));
    }
    if (lane == 0) { wred[wv] = lmin; wred[4 + wv] = lmax; }
    __syncthreads();                       // hist zeroed + wred visible
    const unsigned int umin = min(min(wred[0], wred[1]), min(wred[2], wred[3]));
    const unsigned int umax = max(max(wred[4], wred[5]), max(wred[6], wred[7]));
    const unsigned int rng  = umax - umin;
#pragma unroll
    for (int i = 0; i < 16; ++i) k[i] -= umin;   // uniform shift: order + ties preserved

    int sCur;                              // shift for the level being built
    {
        const int bits = (rng == 0u) ? 0 : (32 - __clz(rng));
        sCur = (bits > 10) ? (bits - 10) : 0;
    }

    // level-0 build: bins span [0, rng>>sCur] <= 1023
#pragma unroll
    for (int i = 0; i < 16; ++i) atomicAdd(&hist[k[i] >> sCur], 1u);
    __syncthreads();

    unsigned int prefix = 0u, rank = KNN - 1;
    int bcnt = 0, nb = 0;
    bool first = true;
    for (;;) {
        // scan 1024 bins; thread t owns bins [4t..4t+3] (one ds_read_b128)
        const uint4 c4 = *(const uint4*)&hist[t * 4];
        const unsigned int ssum = c4.x + c4.y + c4.z + c4.w;
        unsigned int v = ssum;
#pragma unroll
        for (int off = 1; off < 64; off <<= 1) {
            const unsigned int o = __shfl_up(v, off);
            if (lane >= off) v += o;
        }
        if (lane == 63) wsum[wv] = v;
        __syncthreads();
        unsigned int woff = 0;
        for (int i = 0; i < wv; ++i) woff += wsum[i];
        const unsigned int incl = woff + v, excl = incl - ssum;
        if (rank >= excl && rank < incl) {
            const unsigned int cnt[4] = {c4.x, c4.y, c4.z, c4.w};
            unsigned int e = excl;
            for (int j = 0; j < 4; ++j) {
                if (rank < e + cnt[j]) {
                    sc[0] = (unsigned int)(t * 4 + j);
                    sc[1] = rank - e;
                    sc[2] = cnt[j];
                    break;
                }
                e += cnt[j];
            }
        }
        __syncthreads();
        const unsigned int bin = sc[0];
        rank = sc[1];
        bcnt = (int)sc[2];
        prefix = first ? bin : ((prefix << nb) | bin);
        first = false;
        if (bcnt <= 64 || sCur == 0) break;

        // descend: refine within pivot bin on the next (up to) 10 bits
        const int sNext = (sCur > 10) ? (sCur - 10) : 0;
        nb = sCur - sNext;
        __syncthreads();                   // everyone past hist reads
        *(uint4*)&hist[t * 4] = make_uint4(0u, 0u, 0u, 0u);
        __syncthreads();
        const unsigned int mask = (1u << nb) - 1u;
#pragma unroll
        for (int i = 0; i < 16; ++i) {
            if ((k[i] >> sCur) == prefix)
                atomicAdd(&hist[(k[i] >> sNext) & mask], 1u);
        }
        __syncthreads();
        sCur = sNext;
    }

    if (t == 0) { sc[3] = 0u; sc[4] = 0u; }
    __syncthreads();
#pragma unroll
    for (int i = 0; i < 16; ++i) {
        const unsigned int hp = k[i] >> sCur;
        if (hp < prefix) {
            outidx[atomicAdd(&sc[3], 1u)] = i * 256 + t;
        } else if (hp == prefix) {
            const unsigned int slot = atomicAdd(&sc[4], 1u);
            if (slot < 64u) { ckey[slot] = k[i]; cidx[slot] = i * 256 + t; }
        }
    }
    __syncthreads();
    const int defcnt  = (int)sc[3];
    const int candcnt = min((int)sc[4], 64);

    if (wv == 0) {
        const unsigned int k_l = (lane < candcnt) ? ckey[lane] : 0xFFFFFFFFu;
        const int          i_l = (lane < candcnt) ? cidx[lane] : 0x7FFFFFFF;
        int rk = 0;
        for (int j = 0; j < candcnt; ++j) {
            const unsigned int kj = __shfl(k_l, j);
            const int          ij = __shfl(i_l, j);
            if (kj < k_l || (kj == k_l && ij < i_l)) ++rk;
        }
        if (lane < candcnt && rk <= (int)rank) outidx[defcnt + rk] = i_l;
    }
    __syncthreads();
    if (t < KNN) nn[(size_t)bid * KNN + t] = outidx[t];
    if (t == 0) {
        pos_q[(size_t)bid * 3 + 0] = qv.x;
        pos_q[(size_t)bid * 3 + 1] = qv.y;
        pos_q[(size_t)bid * 3 + 2] = qv.z;
    }
}

// ---------------------------------------------------------------------------
// Kernel 2: fused gather + MLP via f16 MFMA 16x16x32 + max over K.
// r11: the gather+pack phase (per-row ~300-op select/convert chain + 12 LDS
// stores, 524K rows -> the hidden ~100 us whale) is GONE. A-fragments load
// directly from the padded x16 rows as aligned 16B global loads:
//   af[kc][mt][j] = X[row][kc*32 + quad*8 + j],  X row = x16[n]  (rel patched
// into k=0..2 on quad-0 lanes). Channel placement identical to r6 -> MFMA
// inputs bitwise identical (absmax stays 0.03125). LDS 24->16 KB (H1 staging
// only, wave-private, still zero barriers). ff[12]/pack registers freed ->
// fits (256,4) without spills.
// ---------------------------------------------------------------------------
__global__ __launch_bounds__(256, 4) void mlp_kernel(
    const float4* __restrict__ pos4, const _Float16* __restrict__ x16,
    const float* __restrict__ b1, const float* __restrict__ b2,
    const float* __restrict__ pos_q, const int* __restrict__ nn,
    const _Float16* __restrict__ wf, float* __restrict__ out)
{
    __shared__ _Float16 sh[4 * 2048];       // 16 KB, wave-private 4 KB regions
    const int t = threadIdx.x;
    const int w = t >> 6, lane = t & 63;
    const int col = lane & 15, quad = lane >> 4;
    const int q = blockIdx.x * 4 + w;       // wave-uniform query id
    const int b = q >> 10;
    const int wbase = w * 2048;
    const int row = lane & 15;

    // neighbor rows this lane needs (same n for the 4 lanes of a quad-column)
    const int n0 = nn[(size_t)q * KNN + row];
    const int n1 = nn[(size_t)q * KNN + 16 + row];

    const _Float16* xb = x16 + (size_t)b * NPTS * XROW;
    const _Float16* x0 = xb + (size_t)n0 * XROW + quad * 8;
    const _Float16* x1 = xb + (size_t)n1 * XROW + quad * 8;

    half8 af[3][2];
    af[0][0] = *(const half8*)(x0);
    af[1][0] = *(const half8*)(x0 + 32);
    af[2][0] = *(const half8*)(x0 + 64);
    af[0][1] = *(const half8*)(x1);
    af[1][1] = *(const half8*)(x1 + 32);
    af[2][1] = *(const half8*)(x1 + 64);

    // rel patch: channels 0..2 live in chunk 0, quad 0, j=0..2
    {
        const float qx = pos_q[(size_t)q * 3 + 0];
        const float qy = pos_q[(size_t)q * 3 + 1];
        const float qz = pos_q[(size_t)q * 3 + 2];
        const float4 pv0 = pos4[(size_t)b * NPTS + n0];
        const float4 pv1 = pos4[(size_t)b * NPTS + n1];
        if (quad == 0) {
            af[0][0][0] = (_Float16)(pv0.x - qx);
            af[0][0][1] = (_Float16)(pv0.y - qy);
            af[0][0][2] = (_Float16)(pv0.z - qz);
            af[0][1][0] = (_Float16)(pv1.x - qx);
            af[0][1][1] = (_Float16)(pv1.y - qy);
            af[0][1][2] = (_Float16)(pv1.z - qz);
        }
    }

    // layer 1: W1 B-frags from global into VGPRs
    half8 w1f[3][4];
#pragma unroll
    for (int kc = 0; kc < 3; ++kc)
#pragma unroll
        for (int nt = 0; nt < 4; ++nt)
            w1f[kc][nt] = *(const half8*)(wf + (size_t)((kc * 4 + nt) * 64 + lane) * 8);

#pragma unroll
    for (int nt = 0; nt < 4; ++nt) {
        const float bv = b1[nt * 16 + col];
        floatx4 acc0 = {bv, bv, bv, bv}, acc1 = acc0;
#pragma unroll
        for (int kc = 0; kc < 3; ++kc) {
            acc0 = __builtin_amdgcn_mfma_f32_16x16x32_f16(af[kc][0], w1f[kc][nt], acc0, 0, 0, 0);
            acc1 = __builtin_amdgcn_mfma_f32_16x16x32_f16(af[kc][1], w1f[kc][nt], acc1, 0, 0, 0);
        }
        const int kc2 = nt >> 1;
        const int quad2 = (((nt & 1) * 16) + col) >> 3;
        const int j2 = col & 7;
#pragma unroll
        for (int mt = 0; mt < 2; ++mt) {
            const floatx4 a = mt ? acc1 : acc0;
#pragma unroll
            for (int reg = 0; reg < 4; ++reg) {
                const int hrow = quad * 4 + reg;
                sh[wbase + ((kc2 * 2 + mt) * 64 + quad2 * 16 + hrow) * 8 + j2] =
                    (_Float16)fmaxf(a[reg], 0.0f);
            }
        }
    }
    // no __syncthreads(): H1 traffic is same-wave, DS pipe in program order

    // layer 2 + max over K
    half8 a2[2][2];
#pragma unroll
    for (int kc2 = 0; kc2 < 2; ++kc2)
#pragma unroll
        for (int mt = 0; mt < 2; ++mt)
            a2[kc2][mt] = *(const half8*)&sh[wbase + ((kc2 * 2 + mt) * 64 + lane) * 8];

    half8 w2f[2][8];
#pragma unroll
    for (int kc2 = 0; kc2 < 2; ++kc2)
#pragma unroll
        for (int nt2 = 0; nt2 < 8; ++nt2)
            w2f[kc2][nt2] = *(const half8*)(wf + (size_t)W1F_HALVES
                                            + (size_t)((kc2 * 8 + nt2) * 64 + lane) * 8);

    float* oq = out + (size_t)q * H2D;
#pragma unroll
    for (int nt2 = 0; nt2 < 8; ++nt2) {
        const float bv = b2[nt2 * 16 + col];
        floatx4 acc0 = {bv, bv, bv, bv}, acc1 = acc0;
#pragma unroll
        for (int kc2 = 0; kc2 < 2; ++kc2) {
            acc0 = __builtin_amdgcn_mfma_f32_16x16x32_f16(a2[kc2][0], w2f[kc2][nt2], acc0, 0, 0, 0);
            acc1 = __builtin_amdgcn_mfma_f32_16x16x32_f16(a2[kc2][1], w2f[kc2][nt2], acc1, 0, 0, 0);
        }
        float mm = fmaxf(fmaxf(fmaxf(acc0[0], acc0[1]), fmaxf(acc0[2], acc0[3])),
                         fmaxf(fmaxf(acc1[0], acc1[1]), fmaxf(acc1[2], acc1[3])));
        mm = fmaxf(mm, 0.0f);
        mm = fmaxf(mm, __shfl_xor(mm, 16));
        mm = fmaxf(mm, __shfl_xor(mm, 32));
        if (lane < 16) oq[nt2 * 16 + lane] = mm;
    }
}

extern "C" void kernel_launch(void* const* d_in, const int* in_sizes, int n_in,
                              void* d_out, int out_size, void* d_ws, size_t ws_size,
                              hipStream_t stream)
{
    const float* pos  = (const float*)d_in[0];
    const float* feat = (const float*)d_in[1];
    const float* W1   = (const float*)d_in[2];
    const float* b1   = (const float*)d_in[3];
    const float* W2   = (const float*)d_in[4];
    const float* b2   = (const float*)d_in[5];
    const int*   idx  = (const int*)d_in[6];   // int64 delivered as int32

    float* pos_q = (float*)d_out;
    float* out   = (float*)d_out + (size_t)BATCH * MQ * 3;
    int*       nn  = (int*)d_ws;
    _Float16*  wf  = (_Float16*)((char*)d_ws + WS_NN_BYTES);
    float4*    p4  = (float4*)((char*)d_ws + WS_P4_OFF);
    _Float16*  x16 = (_Float16*)((char*)d_ws + WS_X16_OFF);   // ~15.8 MB total ws

    const int prep_threads = 1792 + BATCH * NPTS;
    wprep_kernel<<<(prep_threads + 255) / 256, 256, 0, stream>>>(W1, W2, pos, feat,
                                                                 wf, p4, x16);
    knn_kernel<<<BATCH * MQ, 256, 0, stream>>>(p4, idx, pos_q, nn);
    mlp_kernel<<<BATCH * MQ / 4, 256, 0, stream>>>(p4, x16, b1, b2,
                                                   pos_q, nn, wf, out);
}